// Round 1
// baseline (1279.903 us; speedup 1.0000x reference)
//
#include <hip/hip_runtime.h>
#include <cmath>

// Problem constants
#define NB    8
#define CIN   64
#define HIN   256
#define WIN   256
#define COUT  128
#define HOUT  254
#define WOUT  254

// Tiling
#define TILE   32            // spatial tile (both h and w)
#define CPB    16            // output channels per block -> 8 co-groups
#define CCH    4             // cin chunk staged in LDS
#define NCHUNK (CIN / CCH)   // 16
#define XROWS  (TILE + 2)    // 34
#define XPAD   35            // padded LDS row stride (odd -> spreads banks)

// mish(v) = v * tanh(softplus(v)).
// With t = e^v: tanh(log1p(t)) = ((1+t)^2-1)/((1+t)^2+1) = (t^2+2t)/(t^2+2t+2).
// Guard large v (t^2 overflow -> inf/inf NaN); tanh(sp)->1 well before v=20.
__device__ __forceinline__ float mish1(float v) {
    float t = __expf(v);
    float u = t * t + 2.0f * t;
    float r = v * __fdividef(u, u + 2.0f);
    return (v > 20.0f) ? v : r;
}
__device__ __forceinline__ float mish2(float v) { return mish1(mish1(v)); }

__global__ __launch_bounds__(256) void conv3x3_bias_mish2(
    const float* __restrict__ x,      // [NB][CIN][HIN][WIN]
    const float* __restrict__ wgt,    // [COUT][CIN][3][3]
    const float* __restrict__ bias,   // [COUT]
    float* __restrict__ out)          // [NB][COUT][HOUT][WOUT]
{
    __shared__ float sx[CCH][XROWS][XPAD];   // 4*34*35*4B = 19040 B
    __shared__ float sw[CCH * 9][CPB];       // 36*16*4B   =  2304 B

    const int tid = threadIdx.x;
    // co-group fastest in grid.x so sibling blocks (same x tile) run together.
    const int cog = blockIdx.x & 7;          // 0..7
    const int wt  = blockIdx.x >> 3;         // 0..7
    const int ht  = blockIdx.y;              // 0..7
    const int n   = blockIdx.z;              // 0..7

    const int h0  = ht * TILE;
    const int w0  = wt * TILE;
    const int co0 = cog * CPB;

    const int py  = tid >> 3;                // 0..31  (output row within tile)
    const int px4 = (tid & 7) * 4;           // 0,4,...,28 (first of 4 output cols)

    const float* xn = x + (size_t)n * CIN * HIN * WIN;

    float acc[4][CPB];
    #pragma unroll
    for (int p = 0; p < 4; ++p)
        #pragma unroll
        for (int c = 0; c < CPB; ++c) acc[p][c] = 0.0f;

    for (int ch = 0; ch < NCHUNK; ++ch) {
        const int cin0 = ch * CCH;
        __syncthreads();   // protect previous chunk's LDS reads

        // ---- stage x tile: CCH x 34 x 34 (clamped at image edge; clamped
        // rows/cols only feed outputs that are never stored) ----
        for (int i = tid; i < CCH * XROWS * XROWS; i += 256) {
            int cin = i / (XROWS * XROWS);
            int rem = i - cin * (XROWS * XROWS);
            int r   = rem / XROWS;
            int c   = rem - r * XROWS;
            int gh  = h0 + r; if (gh > HIN - 1) gh = HIN - 1;
            int gw  = w0 + c; if (gw > WIN - 1) gw = WIN - 1;
            sx[cin][r][c] = xn[(cin0 + cin) * (HIN * WIN) + gh * WIN + gw];
        }
        // ---- stage weights: sw[cin*9 + k][co], co contiguous (broadcast reads) ----
        for (int i = tid; i < CCH * 9 * CPB; i += 256) {
            int co  = i & (CPB - 1);
            int rk  = i >> 4;                // cin*9 + k
            int cin = rk / 9;
            int k   = rk - cin * 9;
            sw[rk][co] = wgt[((co0 + co) * CIN + cin0 + cin) * 9 + k];
        }
        __syncthreads();

        // ---- compute ----
        for (int cin = 0; cin < CCH; ++cin) {
            #pragma unroll
            for (int kh = 0; kh < 3; ++kh) {
                float xs[6];
                #pragma unroll
                for (int j = 0; j < 6; ++j)
                    xs[j] = sx[cin][py + kh][px4 + j];
                #pragma unroll
                for (int kw = 0; kw < 3; ++kw) {
                    const float* wp = &sw[cin * 9 + kh * 3 + kw][0];
                    float wv[CPB];
                    #pragma unroll
                    for (int c4 = 0; c4 < CPB; c4 += 4) {
                        float4 wq = *(const float4*)(wp + c4);
                        wv[c4 + 0] = wq.x; wv[c4 + 1] = wq.y;
                        wv[c4 + 2] = wq.z; wv[c4 + 3] = wq.w;
                    }
                    #pragma unroll
                    for (int p = 0; p < 4; ++p) {
                        float xv = xs[kw + p];
                        #pragma unroll
                        for (int c = 0; c < CPB; ++c)
                            acc[p][c] = fmaf(xv, wv[c], acc[p][c]);
                    }
                }
            }
        }
    }

    // ---- epilogue: bias + mish(mish(.)) + guarded stores ----
    const int oh = h0 + py;
    if (oh < HOUT) {
        #pragma unroll
        for (int c = 0; c < CPB; ++c) {
            float bs = bias[co0 + c];
            size_t base = ((size_t)(n * COUT + co0 + c) * HOUT + oh) * WOUT;
            #pragma unroll
            for (int p = 0; p < 4; ++p) {
                int ow = w0 + px4 + p;
                if (ow < WOUT)
                    out[base + ow] = mish2(acc[p][c] + bs);
            }
        }
    }
}

extern "C" void kernel_launch(void* const* d_in, const int* in_sizes, int n_in,
                              void* d_out, int out_size, void* d_ws, size_t ws_size,
                              hipStream_t stream) {
    const float* x    = (const float*)d_in[0];
    const float* wgt  = (const float*)d_in[1];
    const float* bias = (const float*)d_in[2];
    float* out        = (float*)d_out;

    dim3 grid(8 * 8, 8, 8);   // (cog*wt, ht, n)
    conv3x3_bias_mish2<<<grid, 256, 0, stream>>>(x, wgt, bias, out);
}

// Round 2
// 526.773 us; speedup vs baseline: 2.4297x; 2.4297x over previous
//
#include <hip/hip_runtime.h>

// Problem constants
#define NBATCH 8
#define CIN    64
#define HIN    256
#define WIN    256
#define COUT   128
#define HOUT   254
#define WOUT   254

// Tiling: block computes 128 pixels (4 rows x 32 cols) x 128 couts.
// K-loop: 9 taps x 2 chunks of 32 ci, 16x16x32 bf16 MFMA.
#define PROWS  4
#define PCOLS  32
#define XR     (PROWS + 2)   // 6 input rows
#define XC     (PCOLS + 2)   // 34 input cols
#define CIP    72            // padded ci stride in bf16 units (72*2B=144B=36 words
                             // -> b128 frag reads hit all 32 banks evenly)

typedef __attribute__((ext_vector_type(8))) short bf16x8;  // MFMA A/B frag (4 VGPRs)
typedef __attribute__((ext_vector_type(4))) float f32x4;   // MFMA C/D frag

__device__ __forceinline__ unsigned short f2bf(float f) {
    union { float f; unsigned u; } v; v.f = f;
    unsigned r = v.u + 0x7FFF + ((v.u >> 16) & 1);   // round-to-nearest-even
    return (unsigned short)(r >> 16);
}

// mish(v) = v*tanh(softplus(v)); t=e^v: tanh(log1p(t)) = (t^2+2t)/(t^2+2t+2).
__device__ __forceinline__ float mish1(float v) {
    float t = __expf(v);
    float u = t * t + 2.0f * t;
    float r = v * __fdividef(u, u + 2.0f);
    return (v > 20.0f) ? v : r;
}
__device__ __forceinline__ float mish2(float v) { return mish1(mish1(v)); }

// Pre-transpose weights: wgt[co][ci][kh][kw] fp32 -> wT[tap][co][ci] bf16.
__global__ __launch_bounds__(256) void wtrans_kernel(
    const float* __restrict__ wgt, unsigned short* __restrict__ wT)
{
    int i = blockIdx.x * 256 + threadIdx.x;       // over 9*128*64 = 73728
    if (i >= 9 * COUT * CIN) return;
    int ci  = i & (CIN - 1);
    int co  = (i >> 6) & (COUT - 1);
    int tap = i >> 13;
    wT[i] = f2bf(wgt[(co * CIN + ci) * 9 + tap]);
}

__global__ __launch_bounds__(256) void conv_mfma(
    const float* __restrict__ x,                  // [NB][CIN][HIN][WIN]
    const float* __restrict__ wgt,                // [COUT][CIN][3][3] (fallback path)
    const float* __restrict__ bias,               // [COUT]
    const unsigned short* __restrict__ wT,        // [9][COUT][CIN] bf16 (ws path)
    int use_ws,
    float* __restrict__ out)                      // [NB][COUT][HOUT][WOUT]
{
    __shared__ unsigned short sx[XR * XC * CIP];  // 6*34*72*2 = 29376 B
    __shared__ unsigned short sw[COUT * CIP];     // 128*72*2  = 18432 B

    const int tid = threadIdx.x;
    const int wt  = blockIdx.x;                   // 0..7  (w tile)
    const int ht  = blockIdx.y;                   // 0..63 (h tile)
    const int n   = blockIdx.z;                   // 0..7
    const int oh0 = ht * PROWS, ow0 = wt * PCOLS;

    const float* xn = x + (size_t)n * CIN * HIN * WIN;

    // ---- stage x tile once: [r][c][ci] bf16, ci contiguous (padded to CIP).
    // Thread reads 2 consecutive ci (coalesced in w), packs to one b32 LDS write.
    for (int j = tid; j < XR * XC * (CIN / 2); j += 256) {
        int c = j % XC;
        int t = j / XC;
        int r = t % XR;
        int p = t / XR;                           // ci pair index 0..31
        int gh = oh0 + r; if (gh > HIN - 1) gh = HIN - 1;   // clamped rows/cols only
        int gw = ow0 + c; if (gw > WIN - 1) gw = WIN - 1;   // feed never-stored outputs
        const float* src = xn + (p * 2) * (HIN * WIN) + gh * WIN + gw;
        float f0 = src[0];
        float f1 = src[HIN * WIN];
        unsigned pk = (unsigned)f2bf(f0) | ((unsigned)f2bf(f1) << 16);
        ((unsigned*)sx)[(r * XC + c) * (CIP / 2) + p] = pk;
    }

    // wave/lane decomposition: 4 waves, each computes 64 px x 64 co
    const int w    = tid >> 6;
    const int lane = tid & 63;
    const int m    = lane & 15;                   // A: pixel row / B: cout col
    const int g    = lane >> 4;                   // k-group (8 ci each)
    const int px0  = (w & 1) * 64;
    const int cb   = (w >> 1) * 64;

    int slot0[4];                                 // (r*XC + c) per M-subtile
    #pragma unroll
    for (int mt = 0; mt < 4; ++mt) {
        int px = px0 + mt * 16 + m;
        slot0[mt] = (px >> 5) * XC + (px & 31);
    }
    int bbase[4];
    #pragma unroll
    for (int nt = 0; nt < 4; ++nt)
        bbase[nt] = (cb + nt * 16 + m) * CIP + g * 8;

    f32x4 acc[4][4];
    #pragma unroll
    for (int a = 0; a < 4; ++a)
        #pragma unroll
        for (int b = 0; b < 4; ++b)
            acc[a][b] = (f32x4){0.f, 0.f, 0.f, 0.f};

    for (int tap = 0; tap < 9; ++tap) {
        int kh = tap / 3, kw = tap - kh * 3;
        __syncthreads();                          // protect prev tap's sw reads
        if (use_ws) {
            const unsigned short* wp = wT + tap * (COUT * CIN);
            #pragma unroll
            for (int k = 0; k < 4; ++k) {
                int q = tid + k * 256;            // 0..1023 16B-chunks
                int co = q >> 3, part = q & 7;
                bf16x8 v = *(const bf16x8*)(wp + q * 8);
                *(bf16x8*)&sw[co * CIP + part * 8] = v;
            }
        } else {
            for (int i = tid; i < COUT * CIN; i += 256) {
                int co = i >> 6, ci = i & 63;
                sw[co * CIP + ci] = f2bf(wgt[(co * CIN + ci) * 9 + tap]);
            }
        }
        __syncthreads();

        const int aoff = (kh * XC + kw) * CIP + g * 8;
        #pragma unroll
        for (int ck = 0; ck < 2; ++ck) {
            bf16x8 av[4], bv[4];
            #pragma unroll
            for (int mt = 0; mt < 4; ++mt)
                av[mt] = *(const bf16x8*)&sx[slot0[mt] * CIP + aoff + ck * 32];
            #pragma unroll
            for (int nt = 0; nt < 4; ++nt)
                bv[nt] = *(const bf16x8*)&sw[bbase[nt] + ck * 32];
            #pragma unroll
            for (int mt = 0; mt < 4; ++mt)
                #pragma unroll
                for (int nt = 0; nt < 4; ++nt)
                    acc[mt][nt] = __builtin_amdgcn_mfma_f32_16x16x32_bf16(
                        av[mt], bv[nt], acc[mt][nt], 0, 0, 0);
        }
    }

    // ---- epilogue: bias + mish2 + store.
    // C/D layout (m89-verified): col(n-dim)=lane&15, row(m-dim)=(lane>>4)*4+reg.
    // The 4 regs are 4 consecutive pixels in w -> contiguous stores.
    #pragma unroll
    for (int nt = 0; nt < 4; ++nt) {
        int co = cb + nt * 16 + m;
        float bs = bias[co];
        float* ob = out + (size_t)(n * COUT + co) * HOUT * WOUT;
        #pragma unroll
        for (int mt = 0; mt < 4; ++mt) {
            int pb = px0 + mt * 16 + g * 4;
            int oh = oh0 + (pb >> 5);
            int ow = ow0 + (pb & 31);
            if (oh >= HOUT) continue;
            float v0 = mish2(acc[mt][nt][0] + bs);
            float v1 = mish2(acc[mt][nt][1] + bs);
            float v2 = mish2(acc[mt][nt][2] + bs);
            float v3 = mish2(acc[mt][nt][3] + bs);
            float* dst = ob + oh * WOUT + ow;
            if (ow + 3 < WOUT) {
                dst[0] = v0; dst[1] = v1; dst[2] = v2; dst[3] = v3;
            } else {
                if (ow     < WOUT) dst[0] = v0;
                if (ow + 1 < WOUT) dst[1] = v1;
                if (ow + 2 < WOUT) dst[2] = v2;
                if (ow + 3 < WOUT) dst[3] = v3;
            }
        }
    }
}

extern "C" void kernel_launch(void* const* d_in, const int* in_sizes, int n_in,
                              void* d_out, int out_size, void* d_ws, size_t ws_size,
                              hipStream_t stream) {
    const float* x    = (const float*)d_in[0];
    const float* wgt  = (const float*)d_in[1];
    const float* bias = (const float*)d_in[2];
    float* out        = (float*)d_out;

    const size_t need = (size_t)9 * COUT * CIN * sizeof(unsigned short);  // 147456 B
    int use_ws = (ws_size >= need) ? 1 : 0;
    unsigned short* wT = (unsigned short*)d_ws;

    if (use_ws) {
        wtrans_kernel<<<(9 * COUT * CIN + 255) / 256, 256, 0, stream>>>(wgt, wT);
    }
    dim3 grid((WOUT + PCOLS - 1) / PCOLS,   // 8
              (HOUT + PROWS - 1) / PROWS,   // 64
              NBATCH);                      // 8
    conv_mfma<<<grid, 256, 0, stream>>>(x, wgt, bias, wT, use_ws, out);
}